// Round 11
// baseline (565.652 us; speedup 1.0000x reference)
//
#include <hip/hip_runtime.h>
#include <math.h>

#define BB 2
#define LL 4
#define CC 128
#define HH 48
#define WWID 176
#define HW 8448   // 48*176

typedef __attribute__((ext_vector_type(8))) short bf16x8;
typedef __attribute__((ext_vector_type(4))) float f32x4;
typedef __attribute__((ext_vector_type(4))) unsigned int u32x4;
typedef __attribute__((ext_vector_type(2))) unsigned int u32x2;
typedef _Float16 f16;
typedef __attribute__((ext_vector_type(8))) _Float16 f16x8;
typedef __attribute__((ext_vector_type(4))) _Float16 f16x4;

__device__ __forceinline__ float b2f(short s){
    unsigned int u = ((unsigned int)(unsigned short)s) << 16;
    union { unsigned int u; float f; } c; c.u = u; return c.f;
}
__device__ __forceinline__ unsigned int f2b(float f){
    union { float f; unsigned int u; } c; c.f = f;
    unsigned int r = c.u + 0x7fffu + ((c.u >> 16) & 1u);
    return r >> 16;
}

// inverse affine from a 4x4 pairwise T block
__device__ __forceinline__ void ainv_from(const float* __restrict__ t, float* a)
{
    float R00=t[0], R01=t[1], t0=t[3];
    float R10=t[4], R11=t[5], t1=t[7];
    float tx = t0 * 0.625f;              // / (RATIO*DS) = /1.6
    float ty = t1 * 0.625f;
    const float cx = WWID/2.0f, cy = HH/2.0f;
    float ftx = cx - (R00*cx + R01*cy) + tx;
    float fty = cy - (R10*cx + R11*cy) + ty;
    float det = R00*R11 - R01*R10;
    float inv = 1.0f/det;
    float i00 =  R11*inv, i01 = -R01*inv, i10 = -R10*inv, i11 = R00*inv;
    a[0]=i00; a[1]=i01; a[2]=-(i00*ftx + i01*fty);
    a[3]=i10; a[4]=i11; a[5]=-(i10*ftx + i11*fty);
}

// ---------------------------------------------------------------------------
// Repack conv weights (OIHW fp32) -> MFMA-fragment order:
//   blk = (tap*8 + kq)*8 + ocblk   (kq = cin/32, ocblk = oc/16)
//   within blk: [l15 16][hi 4][j 8]  -> element W[ocblk*16+l15][kq*32+hi*8+j]
// ---------------------------------------------------------------------------
__global__ __launch_bounds__(256)
void repack3_kernel(const float* __restrict__ Wm, const float* __restrict__ Wg,
                    const float* __restrict__ Wc,
                    short* __restrict__ WmF, short* __restrict__ WuF,
                    short* __restrict__ WcF)
{
    int which = blockIdx.y;
    const float* src = (which==0) ? Wm : (which==1) ? Wg : Wc;
    short* dst       = (which==0) ? WmF : (which==1) ? WuF : WcF;
    int oc_off = (which==1) ? 128 : 0;     // u-gate rows live at [C, 2C)
    int stride = (which==0) ? 256 : 384;
    int idx = blockIdx.x*256 + threadIdx.x;
    if (idx >= 9*8*8*512) return;
    int j     = idx & 7;
    int hi    = (idx >> 3) & 3;
    int l15   = (idx >> 5) & 15;
    int ocblk = (idx >> 9) & 7;
    int kq    = (idx >> 12) & 7;
    int tap   = idx >> 15;
    int oc  = ocblk*16 + l15;
    int cin = kq*32 + hi*8 + j;
    dst[idx] = (short)f2b(src[((size_t)(oc_off+oc)*stride + cin)*9 + tap]);
}

// ---------------------------------------------------------------------------
// x [bl][c][pix] fp32  ->  xT [bl][pix][c] bf16
// ---------------------------------------------------------------------------
__global__ __launch_bounds__(256)
void to_bf16T_kernel(const float* __restrict__ x, short* __restrict__ xT)
{
    int bl = blockIdx.y;
    int pix = blockIdx.x*256 + threadIdx.x;   // grid.x = 33
    const float* src = x + (size_t)bl*CC*HW + pix;
    short* dst = xT + (size_t)bl*HW*CC + (size_t)pix*CC;
    for (int g = 0; g < 8; ++g) {
        unsigned int pk[8];
        #pragma unroll
        for (int c2 = 0; c2 < 8; ++c2) {
            float v0 = src[(size_t)(g*16 + 2*c2    )*HW];
            float v1 = src[(size_t)(g*16 + 2*c2 + 1)*HW];
            pk[c2] = f2b(v0) | (f2b(v1) << 16);
        }
        u32x4 w0 = {pk[0],pk[1],pk[2],pk[3]};
        u32x4 w1 = {pk[4],pk[5],pk[6],pk[7]};
        *(u32x4*)(dst + g*16    ) = w0;
        *(u32x4*)(dst + g*16 + 8) = w1;
    }
}

// ---------------------------------------------------------------------------
// roi factor maps: fac[slot=(b,l2,l1)][pix]  (already * mask[l2])
// ---------------------------------------------------------------------------
__global__ __launch_bounds__(256)
void fac_kernel(const float* __restrict__ T, const float* __restrict__ mask,
                float* __restrict__ fac)
{
    int slot = blockIdx.y;                    // (b<<4)|(l2<<2)|l1
    int pix = blockIdx.x*256 + threadIdx.x;
    int b = slot >> 4, l2 = (slot >> 2) & 3;
    float mk = mask[b*LL + l2];
    float a[6];
    ainv_from(T + slot*16, a);
    float gx = (float)(pix % WWID), gy = (float)(pix / WWID);
    float sx = a[0]*gx + a[1]*gy + a[2];
    float sy = a[3]*gx + a[4]*gy + a[5];
    float x0 = floorf(sx), y0 = floorf(sy);
    float wx = sx-x0, wy = sy-y0;
    int xi=(int)x0, yi=(int)y0;
    bool vx0 = xi>=0 && xi<WWID, vx1 = xi+1>=0 && xi+1<WWID;
    bool vy0 = yi>=0 && yi<HH,   vy1 = yi+1>=0 && yi+1<HH;
    float r = (vx0&&vy0?(1.f-wx)*(1.f-wy):0.f) + (vx1&&vy0?wx*(1.f-wy):0.f)
            + (vx0&&vy1?(1.f-wx)*wy:0.f)       + (vx1&&vy1?wx*wy:0.f);
    fac[(size_t)slot*HW + pix] = r*mk;
}

// ===========================================================================
// msg conv (round-10, proven): one JOB per block-z: z = (b, l1, src).
// block = 128 oc x (8y x 16x) px, 4 waves, K=128x9taps, fragment-order A.
// Output: fp16 partial slab Pm[z][pix][oc] (fac/bias/invrec folded).
// ===========================================================================
__global__ __launch_bounds__(256,3)
void msg_conv_kernel(const short* __restrict__ featT, const float* __restrict__ T,
                     const float* __restrict__ fac, const float* __restrict__ mask,
                     const int* __restrict__ reclen,
                     const short* __restrict__ WmF, const float* __restrict__ bm,
                     f16* __restrict__ Pm, int n_l1)
{
    int z = blockIdx.z;
    int b = z / (n_l1*5);
    int rem = z - b*(n_l1*5);
    int l1 = rem / 5, src = rem % 5;
    if (l1 != 0 && mask[b*LL + l1] == 0.f) return;   // output never consumed
    bool ego = (src == 4);
    int l2 = ego ? l1 : src;
    if (!ego && mask[b*LL + l2] == 0.f) return;      // sender inactive
    bool gather = (!ego) && (l2 != l1);

    int ty = blockIdx.x / 11, tx = blockIdx.x % 11;
    int y0 = ty*8, x0 = tx*16;
    int tid = threadIdx.x;
    int wid = tid >> 6, lane = tid & 63;
    int wr = wid >> 1, wc = wid & 1;
    int l15 = lane & 15, hi = lane >> 4;

    __shared__ short lt[180*128];        // 45 KB
    __shared__ float tw[4][192];
    __shared__ int   tof[4][192];

    const short* in = featT + (size_t)(b*LL + l2)*HW*CC;

    if (gather) {
        // per-row bilinear taps (once), then 4-tap blend staging
        float a6[6];
        ainv_from(T + ((b*LL + l2)*LL + l1)*16, a6);
        float a0=a6[0],a1=a6[1],a2=a6[2],a3=a6[3],a4=a6[4],a5=a6[5];
        for (int r = tid; r < 180; r += 256) {
            int yy = r / 18, xx = r - yy*18;
            int gy = y0 - 1 + yy, gx = x0 - 1 + xx;
            float w00=0.f,w10=0.f,w01=0.f,w11=0.f;
            int o00=0,o10=0,o01=0,o11=0;
            if (gy>=0 && gy<HH && gx>=0 && gx<WWID) {
                float sx = a0*(float)gx + a1*(float)gy + a2;
                float sy = a3*(float)gx + a4*(float)gy + a5;
                float xf = floorf(sx), yf = floorf(sy);
                float wx = sx-xf, wyv = sy-yf;
                int xi=(int)xf, yi=(int)yf;
                bool vx0=xi>=0&&xi<WWID, vx1=xi+1>=0&&xi+1<WWID;
                bool vy0=yi>=0&&yi<HH,   vy1=yi+1>=0&&yi+1<HH;
                int xc0=min(max(xi,0),WWID-1), xc1=min(max(xi+1,0),WWID-1);
                int yc0=min(max(yi,0),HH-1),   yc1=min(max(yi+1,0),HH-1);
                o00=(yc0*WWID+xc0)*CC; o10=(yc0*WWID+xc1)*CC;
                o01=(yc1*WWID+xc0)*CC; o11=(yc1*WWID+xc1)*CC;
                w00=(vx0&&vy0)?(1.f-wx)*(1.f-wyv):0.f;
                w10=(vx1&&vy0)?wx*(1.f-wyv):0.f;
                w01=(vx0&&vy1)?(1.f-wx)*wyv:0.f;
                w11=(vx1&&vy1)?wx*wyv:0.f;
            }
            tw[0][r]=w00; tw[1][r]=w10; tw[2][r]=w01; tw[3][r]=w11;
            tof[0][r]=o00; tof[1][r]=o10; tof[2][r]=o01; tof[3][r]=o11;
        }
        __syncthreads();
        for (int i = tid; i < 180*16; i += 256) {
            int row = i >> 4, cg = i & 15;
            float w00=tw[0][row], w10=tw[1][row], w01=tw[2][row], w11=tw[3][row];
            int o00=tof[0][row], o10=tof[1][row], o01=tof[2][row], o11=tof[3][row];
            bf16x8 t00 = *(const bf16x8*)(in + o00 + cg*8);
            bf16x8 t10 = *(const bf16x8*)(in + o10 + cg*8);
            bf16x8 t01 = *(const bf16x8*)(in + o01 + cg*8);
            bf16x8 t11 = *(const bf16x8*)(in + o11 + cg*8);
            unsigned int po[4];
            #pragma unroll
            for (int j=0;j<8;j+=2) {
                float f0 = w00*b2f(t00[j]) + w10*b2f(t10[j])
                         + w01*b2f(t01[j]) + w11*b2f(t11[j]);
                float f1 = w00*b2f(t00[j+1]) + w10*b2f(t10[j+1])
                         + w01*b2f(t01[j+1]) + w11*b2f(t11[j+1]);
                po[j>>1] = f2b(f0) | (f2b(f1)<<16);
            }
            u32x4 val = {po[0],po[1],po[2],po[3]};
            int byte = row*256 + ((cg*16) ^ ((row&7)<<4));
            *(u32x4*)((char*)lt + byte) = val;
        }
    } else {
        for (int i = tid; i < 180*16; i += 256) {
            int row = i >> 4, cg = i & 15;
            int yy = row / 18, xx = row - yy*18;
            int gy = y0 - 1 + yy, gx = x0 - 1 + xx;
            u32x4 val = {0,0,0,0};
            if (gy>=0 && gy<HH && gx>=0 && gx<WWID)
                val = *(const u32x4*)(in + (size_t)(gy*WWID+gx)*CC + cg*8);
            int byte = row*256 + ((cg*16) ^ ((row&7)<<4));
            *(u32x4*)((char*)lt + byte) = val;
        }
    }
    __syncthreads();

    f32x4 acc[4][4];
    #pragma unroll
    for (int m=0;m<4;++m)
        #pragma unroll
        for (int n=0;n<4;++n) acc[m][n] = (f32x4){0.f,0.f,0.f,0.f};

    const int kqbase = ego ? 4 : 0;
    const short* wlane = WmF + l15*32 + hi*8;
    for (int tap=0; tap<9; ++tap) {
        int dy = tap/3, dx = tap - dy*3;
        #pragma unroll
        for (int kk=0; kk<4; ++kk) {
            const short* wt = wlane + (size_t)(((tap*8 + kqbase + kk)*8 + wr*4))*512;
            bf16x8 av[4];
            #pragma unroll
            for (int m=0;m<4;++m)
                av[m] = *(const bf16x8*)(wt + m*512);
            bf16x8 bv[4];
            #pragma unroll
            for (int n=0;n<4;++n) {
                int pos = (wc*4 + n + dy)*18 + dx + l15;
                int byte = pos*256 + ((kk*64 + hi*16) ^ ((pos&7)<<4));
                bv[n] = *(const bf16x8*)((const char*)lt + byte);
            }
            #pragma unroll
            for (int m=0;m<4;++m)
                #pragma unroll
                for (int n=0;n<4;++n)
                    acc[m][n] = __builtin_amdgcn_mfma_f32_16x16x32_bf16(
                        av[m], bv[n], acc[m][n], 0, 0, 0);
        }
    }

    // per-pixel scale: fac (pair) or facsum (ego), times invrec (precision)
    float invrec = 1.0f / (float)reclen[b];
    float fsc[4];
    if (ego) {
        #pragma unroll
        for (int n=0;n<4;++n) fsc[n] = 0.f;
        for (int j=0;j<LL;++j) {
            if (mask[b*LL + j] == 0.f) continue;
            const float* fp = fac + (size_t)(b*16 + j*4 + l1)*HW;
            #pragma unroll
            for (int n=0;n<4;++n)
                fsc[n] += fp[(y0 + wc*4 + n)*WWID + x0 + l15];
        }
    } else {
        const float* fp = fac + (size_t)(b*16 + l2*4 + l1)*HW;
        #pragma unroll
        for (int n=0;n<4;++n)
            fsc[n] = fp[(y0 + wc*4 + n)*WWID + x0 + l15];
    }
    #pragma unroll
    for (int n=0;n<4;++n) fsc[n] *= invrec;

    f16* outp = Pm + (size_t)z*HW*CC;
    #pragma unroll
    for (int m=0;m<4;++m) {
        f32x4 b4 = {0.f,0.f,0.f,0.f};
        if (ego) b4 = *(const f32x4*)(bm + wr*64 + m*16 + hi*4);
        #pragma unroll
        for (int n=0;n<4;++n) {
            int pix = (y0 + wc*4 + n)*WWID + x0 + l15;
            int oc  = wr*64 + m*16 + hi*4;
            f32x4 v = (acc[m][n] + b4) * fsc[n];
            f16x4 h = {(f16)v[0], (f16)v[1], (f16)v[2], (f16)v[3]};
            *(f16x4*)(outp + (size_t)pix*CC + oc) = h;
        }
    }
}

// ---------------------------------------------------------------------------
// reduce: aggT[zi][pix][c] bf16 = sum of active job slabs (invrec pre-folded)
// ---------------------------------------------------------------------------
__global__ __launch_bounds__(256)
void reduce_agg_kernel(const f16* __restrict__ Pm, const float* __restrict__ mask,
                       short* __restrict__ aggT, int n_l1)
{
    int zi = blockIdx.y;                 // b*n_l1 + l1
    int b = zi / n_l1, l1 = zi % n_l1;
    if (l1 != 0 && mask[b*LL + l1] == 0.f) return;
    int pix = blockIdx.x*256 + threadIdx.x;
    bool act[4];
    #pragma unroll
    for (int j=0;j<LL;++j) act[j] = (mask[b*LL + j] != 0.f);
    const f16* base = Pm + (size_t)(zi*5)*HW*CC + (size_t)pix*CC;
    short* dst = aggT + (size_t)zi*HW*CC + (size_t)pix*CC;
    for (int cg=0; cg<16; ++cg) {
        float s[8];
        f16x8 e = *(const f16x8*)(base + (size_t)4*HW*CC + cg*8);
        #pragma unroll
        for (int j8=0;j8<8;++j8) s[j8] = (float)e[j8];
        #pragma unroll
        for (int j=0;j<4;++j) {
            if (!act[j]) continue;
            f16x8 p = *(const f16x8*)(base + (size_t)j*HW*CC + cg*8);
            #pragma unroll
            for (int j8=0;j8<8;++j8) s[j8] += (float)p[j8];
        }
        unsigned int pk[4];
        #pragma unroll
        for (int j2=0;j2<4;++j2)
            pk[j2] = f2b(s[2*j2]) | (f2b(s[2*j2+1])<<16);
        u32x4 w = {pk[0],pk[1],pk[2],pk[3]};
        *(u32x4*)(dst + cg*8) = w;
    }
}

// ===========================================================================
// fused GRU (round-5-validated wave structure + round-10 fragment A-loads):
// stage feat -> MFMA(U,C) -> stage agg -> MFMA(U,C) -> sigmoid/tanh -> bf16.
// 512 thr = 8 waves (wr 2 x wc 4); wave = 64 oc x (2y x 16x) for BOTH gates;
// acc aU[4][2]+aC[4][2] = 64 regs.  No partial slabs.
// ===========================================================================
__global__ __launch_bounds__(512,4)
void gru_fused_kernel(const short* __restrict__ featT, const short* __restrict__ aggT,
                      const float* __restrict__ mask,
                      const short* __restrict__ WuF, const short* __restrict__ WcF,
                      const float* __restrict__ bgU, const float* __restrict__ bc,
                      short* __restrict__ outT, int n_l1)
{
    int z = blockIdx.z;
    int b = z / n_l1, l1 = z % n_l1;
    if (l1 != 0 && mask[b*LL + l1] == 0.f) return;

    int ty = blockIdx.x / 11, tx = blockIdx.x % 11;
    int y0 = ty*8, x0 = tx*16;
    int tid = threadIdx.x;
    int wid = tid >> 6, lane = tid & 63;
    int wr = wid >> 2, wc = wid & 3;     // wr: 0..1 (64 oc), wc: 0..3 (2 rows)
    int l15 = lane & 15, hi = lane >> 4;

    __shared__ short lt[180*128];  // 45 KB

    f32x4 aU[4][2], aC[4][2];
    #pragma unroll
    for (int m=0;m<4;++m)
        #pragma unroll
        for (int n=0;n<2;++n) {
            aU[m][n] = (f32x4){0.f,0.f,0.f,0.f};
            aC[m][n] = (f32x4){0.f,0.f,0.f,0.f};
        }

    const short* wlaneU = WuF + l15*32 + hi*8;
    const short* wlaneC = WcF + l15*32 + hi*8;

    for (int s = 0; s < 2; ++s) {
        const short* in = (s==0) ? featT + (size_t)(b*LL + l1)*HW*CC
                                 : aggT  + (size_t)(b*n_l1 + l1)*HW*CC;
        if (s) __syncthreads();           // MFMA readers of stage-0 done
        for (int i = tid; i < 180*16; i += 512) {
            int row = i >> 4, cg = i & 15;
            int yy = row / 18, xx = row - yy*18;
            int gy = y0 - 1 + yy, gx = x0 - 1 + xx;
            u32x4 val = {0,0,0,0};
            if (gy>=0 && gy<HH && gx>=0 && gx<WWID)
                val = *(const u32x4*)(in + (size_t)(gy*WWID+gx)*CC + cg*8);
            int byte = row*256 + ((cg*16) ^ ((row&7)<<4));
            *(u32x4*)((char*)lt + byte) = val;
        }
        __syncthreads();

        int kqbase = s*4;
        for (int tap=0; tap<9; ++tap) {
            int dy = tap/3, dx = tap - dy*3;
            #pragma unroll
            for (int kk=0; kk<4; ++kk) {
                size_t blkoff = (size_t)(((tap*8 + kqbase + kk)*8 + wr*4))*512;
                bf16x8 bv[2];
                #pragma unroll
                for (int n=0;n<2;++n) {
                    int pos = (wc*2 + n + dy)*18 + dx + l15;
                    int byte = pos*256 + ((kk*64 + hi*16) ^ ((pos&7)<<4));
                    bv[n] = *(const bf16x8*)((const char*)lt + byte);
                }
                bf16x8 avU[4], avC[4];
                #pragma unroll
                for (int m=0;m<4;++m) {
                    avU[m] = *(const bf16x8*)(wlaneU + blkoff + m*512);
                    avC[m] = *(const bf16x8*)(wlaneC + blkoff + m*512);
                }
                #pragma unroll
                for (int m=0;m<4;++m)
                    #pragma unroll
                    for (int n=0;n<2;++n) {
                        aU[m][n] = __builtin_amdgcn_mfma_f32_16x16x32_bf16(
                            avU[m], bv[n], aU[m][n], 0, 0, 0);
                        aC[m][n] = __builtin_amdgcn_mfma_f32_16x16x32_bf16(
                            avC[m], bv[n], aC[m][n], 0, 0, 0);
                    }
            }
        }
    }

    short* outp = outT + (size_t)z*HW*CC;
    #pragma unroll
    for (int m=0;m<4;++m) {
        f32x4 bu4 = *(const f32x4*)(bgU + wr*64 + m*16 + hi*4);
        f32x4 bc4 = *(const f32x4*)(bc  + wr*64 + m*16 + hi*4);
        #pragma unroll
        for (int n=0;n<2;++n) {
            int pix = (y0 + wc*2 + n)*WWID + x0 + l15;
            int oc  = wr*64 + m*16 + hi*4;
            f32x4 u4 = aU[m][n] + bu4;
            f32x4 c4 = aC[m][n] + bc4;
            float r[4];
            #pragma unroll
            for (int j=0;j<4;++j) {
                float sig = 1.f/(1.f + expf(-u4[j]));
                r[j] = sig * tanhf(c4[j]);
            }
            u32x2 pk;
            pk[0] = f2b(r[0]) | (f2b(r[1])<<16);
            pk[1] = f2b(r[2]) | (f2b(r[3])<<16);
            *(u32x2*)(outp + (size_t)pix*CC + oc) = pk;
        }
    }
}

// ---------------------------------------------------------------------------
// final 1x1 MLP:  out[b][oc][pix] = sum_c feat2T[b][pix][c]*W[oc][c] + bias
// ---------------------------------------------------------------------------
__global__ __launch_bounds__(256)
void mlp_kernel(const short* __restrict__ feat2T, const float* __restrict__ Wm,
                const float* __restrict__ bmlp, float* __restrict__ out)
{
    int b = blockIdx.z, oc0 = blockIdx.y*32;
    int pix = blockIdx.x*256 + threadIdx.x;
    const short* src = feat2T + (size_t)b*HW*CC + (size_t)pix*CC;
    float acc[32];
    #pragma unroll
    for (int oc=0;oc<32;++oc) acc[oc]=0.f;
    for (int c8 = 0; c8 < 16; ++c8) {
        bf16x8 v = *(const bf16x8*)(src + c8*8);
        float f[8];
        #pragma unroll
        for (int j=0;j<8;++j) f[j] = b2f(v[j]);
        #pragma unroll
        for (int oc=0; oc<32; ++oc) {
            const float* w = Wm + (size_t)(oc0+oc)*CC + c8*8;
            #pragma unroll
            for (int j=0;j<8;++j) acc[oc] = fmaf(f[j], w[j], acc[oc]);
        }
    }
    #pragma unroll
    for (int oc=0;oc<32;++oc)
        out[((size_t)b*CC + oc0+oc)*HW + pix] = acc[oc] + bmlp[oc0+oc];
}

// ---------------------------------------------------------------------------
extern "C" void kernel_launch(void* const* d_in, const int* in_sizes, int n_in,
                              void* d_out, int out_size, void* d_ws, size_t ws_size,
                              hipStream_t stream)
{
    const float* x     = (const float*)d_in[0];
    const float* mask  = (const float*)d_in[1];
    const float* T     = (const float*)d_in[2];
    const int*   recl  = (const int*)  d_in[3];
    const float* Wmsg  = (const float*)d_in[4];
    const float* bmsg  = (const float*)d_in[5];
    const float* Wg    = (const float*)d_in[6];
    const float* bg    = (const float*)d_in[7];
    const float* Wc    = (const float*)d_in[8];
    const float* bc    = (const float*)d_in[9];
    const float* Wmlp  = (const float*)d_in[10];
    const float* bmlp  = (const float*)d_in[11];
    float* out = (float*)d_out;

    char* w = (char*)d_ws;
    short* xT   = (short*)w;          w += (size_t)BB*LL*HW*CC*2;      // 17.3 MB
    float* fac  = (float*)w;          w += (size_t)32*HW*4;            // 1.1 MB
    short* WmF  = (short*)w;          w += (size_t)9*128*256*2;
    short* WuF  = (short*)w;          w += (size_t)9*128*256*2;
    short* WcF  = (short*)w;          w += (size_t)9*128*256*2;
    f16*   Pm   = (f16*)w;            w += (size_t)40*HW*CC*2;         // 86.5 MB
    short* aggT = (short*)w;          w += (size_t)BB*LL*HW*CC*2;      // 17.3 MB
    short* f1T  = (short*)w;          w += (size_t)BB*LL*HW*CC*2;      // 17.3 MB
    short* f2T  = (short*)w;          w += (size_t)BB*HW*CC*2;         // 4.3 MB

    repack3_kernel<<<dim3(1152,3), 256, 0, stream>>>(Wmsg, Wg, Wc, WmF, WuF, WcF);
    to_bf16T_kernel<<<dim3(33, BB*LL), 256, 0, stream>>>(x, xT);
    fac_kernel<<<dim3(33, 32), 256, 0, stream>>>(T, mask, fac);

    // ---- iteration 1 ----
    msg_conv_kernel<<<dim3(66, 1, BB*LL*5), 256, 0, stream>>>(
        xT, T, fac, mask, recl, WmF, bmsg, Pm, LL);
    reduce_agg_kernel<<<dim3(33, BB*LL), 256, 0, stream>>>(Pm, mask, aggT, LL);
    gru_fused_kernel<<<dim3(66, 1, BB*LL), 512, 0, stream>>>(
        xT, aggT, mask, WuF, WcF, bg + CC, bc, f1T, LL);

    // ---- iteration 2 (only l1=0 consumed) ----
    msg_conv_kernel<<<dim3(66, 1, BB*5), 256, 0, stream>>>(
        f1T, T, fac, mask, recl, WmF, bmsg, Pm, 1);
    reduce_agg_kernel<<<dim3(33, BB), 256, 0, stream>>>(Pm, mask, aggT, 1);
    gru_fused_kernel<<<dim3(66, 1, BB), 512, 0, stream>>>(
        f1T, aggT, mask, WuF, WcF, bg + CC, bc, f2T, 1);

    // ---- final MLP ----
    mlp_kernel<<<dim3(33, 4, BB), 256, 0, stream>>>(f2T, Wmlp, bmlp, out);
}

// Round 12
// 536.638 us; speedup vs baseline: 1.0541x; 1.0541x over previous
//
#include <hip/hip_runtime.h>
#include <math.h>

#define BB 2
#define LL 4
#define CC 128
#define HH 48
#define WWID 176
#define HW 8448   // 48*176

typedef __attribute__((ext_vector_type(8))) short bf16x8;
typedef __attribute__((ext_vector_type(4))) float f32x4;
typedef __attribute__((ext_vector_type(4))) unsigned int u32x4;
typedef __attribute__((ext_vector_type(2))) unsigned int u32x2;
typedef _Float16 f16;
typedef __attribute__((ext_vector_type(8))) _Float16 f16x8;
typedef __attribute__((ext_vector_type(4))) _Float16 f16x4;

__device__ __forceinline__ float b2f(short s){
    unsigned int u = ((unsigned int)(unsigned short)s) << 16;
    union { unsigned int u; float f; } c; c.u = u; return c.f;
}
__device__ __forceinline__ unsigned int f2b(float f){
    union { float f; unsigned int u; } c; c.f = f;
    unsigned int r = c.u + 0x7fffu + ((c.u >> 16) & 1u);
    return r >> 16;
}

// inverse affine from a 4x4 pairwise T block
__device__ __forceinline__ void ainv_from(const float* __restrict__ t, float* a)
{
    float R00=t[0], R01=t[1], t0=t[3];
    float R10=t[4], R11=t[5], t1=t[7];
    float tx = t0 * 0.625f;              // / (RATIO*DS) = /1.6
    float ty = t1 * 0.625f;
    const float cx = WWID/2.0f, cy = HH/2.0f;
    float ftx = cx - (R00*cx + R01*cy) + tx;
    float fty = cy - (R10*cx + R11*cy) + ty;
    float det = R00*R11 - R01*R10;
    float inv = 1.0f/det;
    float i00 =  R11*inv, i01 = -R01*inv, i10 = -R10*inv, i11 = R00*inv;
    a[0]=i00; a[1]=i01; a[2]=-(i00*ftx + i01*fty);
    a[3]=i10; a[4]=i11; a[5]=-(i10*ftx + i11*fty);
}

// ---------------------------------------------------------------------------
// Repack conv weights (OIHW fp32) -> MFMA-fragment order:
//   blk = (tap*8 + kq)*8 + ocblk   (kq = cin/32, ocblk = oc/16)
//   within blk: [l15 16][hi 4][j 8]  -> element W[ocblk*16+l15][kq*32+hi*8+j]
// ---------------------------------------------------------------------------
__global__ __launch_bounds__(256)
void repack3_kernel(const float* __restrict__ Wm, const float* __restrict__ Wg,
                    const float* __restrict__ Wc,
                    short* __restrict__ WmF, short* __restrict__ WuF,
                    short* __restrict__ WcF)
{
    int which = blockIdx.y;
    const float* src = (which==0) ? Wm : (which==1) ? Wg : Wc;
    short* dst       = (which==0) ? WmF : (which==1) ? WuF : WcF;
    int oc_off = (which==1) ? 128 : 0;     // u-gate rows live at [C, 2C)
    int stride = (which==0) ? 256 : 384;
    int idx = blockIdx.x*256 + threadIdx.x;
    if (idx >= 9*8*8*512) return;
    int j     = idx & 7;
    int hi    = (idx >> 3) & 3;
    int l15   = (idx >> 5) & 15;
    int ocblk = (idx >> 9) & 7;
    int kq    = (idx >> 12) & 7;
    int tap   = idx >> 15;
    int oc  = ocblk*16 + l15;
    int cin = kq*32 + hi*8 + j;
    dst[idx] = (short)f2b(src[((size_t)(oc_off+oc)*stride + cin)*9 + tap]);
}

// ---------------------------------------------------------------------------
// x [bl][c][pix] fp32  ->  xT [bl][pix][c] bf16
// ---------------------------------------------------------------------------
__global__ __launch_bounds__(256)
void to_bf16T_kernel(const float* __restrict__ x, short* __restrict__ xT)
{
    int bl = blockIdx.y;
    int pix = blockIdx.x*256 + threadIdx.x;   // grid.x = 33
    const float* src = x + (size_t)bl*CC*HW + pix;
    short* dst = xT + (size_t)bl*HW*CC + (size_t)pix*CC;
    for (int g = 0; g < 8; ++g) {
        unsigned int pk[8];
        #pragma unroll
        for (int c2 = 0; c2 < 8; ++c2) {
            float v0 = src[(size_t)(g*16 + 2*c2    )*HW];
            float v1 = src[(size_t)(g*16 + 2*c2 + 1)*HW];
            pk[c2] = f2b(v0) | (f2b(v1) << 16);
        }
        u32x4 w0 = {pk[0],pk[1],pk[2],pk[3]};
        u32x4 w1 = {pk[4],pk[5],pk[6],pk[7]};
        *(u32x4*)(dst + g*16    ) = w0;
        *(u32x4*)(dst + g*16 + 8) = w1;
    }
}

// ---------------------------------------------------------------------------
// roi factor maps: fac[slot=(b,l2,l1)][pix]  (already * mask[l2])
// ---------------------------------------------------------------------------
__global__ __launch_bounds__(256)
void fac_kernel(const float* __restrict__ T, const float* __restrict__ mask,
                float* __restrict__ fac)
{
    int slot = blockIdx.y;                    // (b<<4)|(l2<<2)|l1
    int pix = blockIdx.x*256 + threadIdx.x;
    int b = slot >> 4, l2 = (slot >> 2) & 3;
    float mk = mask[b*LL + l2];
    float a[6];
    ainv_from(T + slot*16, a);
    float gx = (float)(pix % WWID), gy = (float)(pix / WWID);
    float sx = a[0]*gx + a[1]*gy + a[2];
    float sy = a[3]*gx + a[4]*gy + a[5];
    float x0 = floorf(sx), y0 = floorf(sy);
    float wx = sx-x0, wy = sy-y0;
    int xi=(int)x0, yi=(int)y0;
    bool vx0 = xi>=0 && xi<WWID, vx1 = xi+1>=0 && xi+1<WWID;
    bool vy0 = yi>=0 && yi<HH,   vy1 = yi+1>=0 && yi+1<HH;
    float r = (vx0&&vy0?(1.f-wx)*(1.f-wy):0.f) + (vx1&&vy0?wx*(1.f-wy):0.f)
            + (vx0&&vy1?(1.f-wx)*wy:0.f)       + (vx1&&vy1?wx*wy:0.f);
    fac[(size_t)slot*HW + pix] = r*mk;
}

// ===========================================================================
// msg conv (round-10, proven): one JOB per block-z: z = (b, l1, src).
// block = 128 oc x (8y x 16x) px, 4 waves, K=128x9taps, fragment-order A.
// Output: fp16 partial slab Pm[z][pix][oc] (fac/bias/invrec folded).
// ===========================================================================
__global__ __launch_bounds__(256,3)
void msg_conv_kernel(const short* __restrict__ featT, const float* __restrict__ T,
                     const float* __restrict__ fac, const float* __restrict__ mask,
                     const int* __restrict__ reclen,
                     const short* __restrict__ WmF, const float* __restrict__ bm,
                     f16* __restrict__ Pm, int n_l1)
{
    int z = blockIdx.z;
    int b = z / (n_l1*5);
    int rem = z - b*(n_l1*5);
    int l1 = rem / 5, src = rem % 5;
    if (l1 != 0 && mask[b*LL + l1] == 0.f) return;   // output never consumed
    bool ego = (src == 4);
    int l2 = ego ? l1 : src;
    if (!ego && mask[b*LL + l2] == 0.f) return;      // sender inactive
    bool gather = (!ego) && (l2 != l1);

    int ty = blockIdx.x / 11, tx = blockIdx.x % 11;
    int y0 = ty*8, x0 = tx*16;
    int tid = threadIdx.x;
    int wid = tid >> 6, lane = tid & 63;
    int wr = wid >> 1, wc = wid & 1;
    int l15 = lane & 15, hi = lane >> 4;

    __shared__ short lt[180*128];        // 45 KB
    __shared__ float tw[4][192];
    __shared__ int   tof[4][192];

    const short* in = featT + (size_t)(b*LL + l2)*HW*CC;

    if (gather) {
        // per-row bilinear taps (once), then 4-tap blend staging
        float a6[6];
        ainv_from(T + ((b*LL + l2)*LL + l1)*16, a6);
        float a0=a6[0],a1=a6[1],a2=a6[2],a3=a6[3],a4=a6[4],a5=a6[5];
        for (int r = tid; r < 180; r += 256) {
            int yy = r / 18, xx = r - yy*18;
            int gy = y0 - 1 + yy, gx = x0 - 1 + xx;
            float w00=0.f,w10=0.f,w01=0.f,w11=0.f;
            int o00=0,o10=0,o01=0,o11=0;
            if (gy>=0 && gy<HH && gx>=0 && gx<WWID) {
                float sx = a0*(float)gx + a1*(float)gy + a2;
                float sy = a3*(float)gx + a4*(float)gy + a5;
                float xf = floorf(sx), yf = floorf(sy);
                float wx = sx-xf, wyv = sy-yf;
                int xi=(int)xf, yi=(int)yf;
                bool vx0=xi>=0&&xi<WWID, vx1=xi+1>=0&&xi+1<WWID;
                bool vy0=yi>=0&&yi<HH,   vy1=yi+1>=0&&yi+1<HH;
                int xc0=min(max(xi,0),WWID-1), xc1=min(max(xi+1,0),WWID-1);
                int yc0=min(max(yi,0),HH-1),   yc1=min(max(yi+1,0),HH-1);
                o00=(yc0*WWID+xc0)*CC; o10=(yc0*WWID+xc1)*CC;
                o01=(yc1*WWID+xc0)*CC; o11=(yc1*WWID+xc1)*CC;
                w00=(vx0&&vy0)?(1.f-wx)*(1.f-wyv):0.f;
                w10=(vx1&&vy0)?wx*(1.f-wyv):0.f;
                w01=(vx0&&vy1)?(1.f-wx)*wyv:0.f;
                w11=(vx1&&vy1)?wx*wyv:0.f;
            }
            tw[0][r]=w00; tw[1][r]=w10; tw[2][r]=w01; tw[3][r]=w11;
            tof[0][r]=o00; tof[1][r]=o10; tof[2][r]=o01; tof[3][r]=o11;
        }
        __syncthreads();
        for (int i = tid; i < 180*16; i += 256) {
            int row = i >> 4, cg = i & 15;
            float w00=tw[0][row], w10=tw[1][row], w01=tw[2][row], w11=tw[3][row];
            int o00=tof[0][row], o10=tof[1][row], o01=tof[2][row], o11=tof[3][row];
            bf16x8 t00 = *(const bf16x8*)(in + o00 + cg*8);
            bf16x8 t10 = *(const bf16x8*)(in + o10 + cg*8);
            bf16x8 t01 = *(const bf16x8*)(in + o01 + cg*8);
            bf16x8 t11 = *(const bf16x8*)(in + o11 + cg*8);
            unsigned int po[4];
            #pragma unroll
            for (int j=0;j<8;j+=2) {
                float f0 = w00*b2f(t00[j]) + w10*b2f(t10[j])
                         + w01*b2f(t01[j]) + w11*b2f(t11[j]);
                float f1 = w00*b2f(t00[j+1]) + w10*b2f(t10[j+1])
                         + w01*b2f(t01[j+1]) + w11*b2f(t11[j+1]);
                po[j>>1] = f2b(f0) | (f2b(f1)<<16);
            }
            u32x4 val = {po[0],po[1],po[2],po[3]};
            int byte = row*256 + ((cg*16) ^ ((row&7)<<4));
            *(u32x4*)((char*)lt + byte) = val;
        }
    } else {
        for (int i = tid; i < 180*16; i += 256) {
            int row = i >> 4, cg = i & 15;
            int yy = row / 18, xx = row - yy*18;
            int gy = y0 - 1 + yy, gx = x0 - 1 + xx;
            u32x4 val = {0,0,0,0};
            if (gy>=0 && gy<HH && gx>=0 && gx<WWID)
                val = *(const u32x4*)(in + (size_t)(gy*WWID+gx)*CC + cg*8);
            int byte = row*256 + ((cg*16) ^ ((row&7)<<4));
            *(u32x4*)((char*)lt + byte) = val;
        }
    }
    __syncthreads();

    f32x4 acc[4][4];
    #pragma unroll
    for (int m=0;m<4;++m)
        #pragma unroll
        for (int n=0;n<4;++n) acc[m][n] = (f32x4){0.f,0.f,0.f,0.f};

    const int kqbase = ego ? 4 : 0;
    const short* wlane = WmF + l15*32 + hi*8;
    __builtin_amdgcn_s_setprio(1);
    for (int tap=0; tap<9; ++tap) {
        int dy = tap/3, dx = tap - dy*3;
        #pragma unroll
        for (int kk=0; kk<4; ++kk) {
            const short* wt = wlane + (size_t)(((tap*8 + kqbase + kk)*8 + wr*4))*512;
            bf16x8 av[4];
            #pragma unroll
            for (int m=0;m<4;++m)
                av[m] = *(const bf16x8*)(wt + m*512);
            bf16x8 bv[4];
            #pragma unroll
            for (int n=0;n<4;++n) {
                int pos = (wc*4 + n + dy)*18 + dx + l15;
                int byte = pos*256 + ((kk*64 + hi*16) ^ ((pos&7)<<4));
                bv[n] = *(const bf16x8*)((const char*)lt + byte);
            }
            #pragma unroll
            for (int m=0;m<4;++m)
                #pragma unroll
                for (int n=0;n<4;++n)
                    acc[m][n] = __builtin_amdgcn_mfma_f32_16x16x32_bf16(
                        av[m], bv[n], acc[m][n], 0, 0, 0);
        }
    }
    __builtin_amdgcn_s_setprio(0);

    // per-pixel scale: fac (pair) or facsum (ego), times invrec (precision)
    float invrec = 1.0f / (float)reclen[b];
    float fsc[4];
    if (ego) {
        #pragma unroll
        for (int n=0;n<4;++n) fsc[n] = 0.f;
        for (int j=0;j<LL;++j) {
            if (mask[b*LL + j] == 0.f) continue;
            const float* fp = fac + (size_t)(b*16 + j*4 + l1)*HW;
            #pragma unroll
            for (int n=0;n<4;++n)
                fsc[n] += fp[(y0 + wc*4 + n)*WWID + x0 + l15];
        }
    } else {
        const float* fp = fac + (size_t)(b*16 + l2*4 + l1)*HW;
        #pragma unroll
        for (int n=0;n<4;++n)
            fsc[n] = fp[(y0 + wc*4 + n)*WWID + x0 + l15];
    }
    #pragma unroll
    for (int n=0;n<4;++n) fsc[n] *= invrec;

    f16* outp = Pm + (size_t)z*HW*CC;
    #pragma unroll
    for (int m=0;m<4;++m) {
        f32x4 b4 = {0.f,0.f,0.f,0.f};
        if (ego) b4 = *(const f32x4*)(bm + wr*64 + m*16 + hi*4);
        #pragma unroll
        for (int n=0;n<4;++n) {
            int pix = (y0 + wc*4 + n)*WWID + x0 + l15;
            int oc  = wr*64 + m*16 + hi*4;
            f32x4 v = (acc[m][n] + b4) * fsc[n];
            f16x4 h = {(f16)v[0], (f16)v[1], (f16)v[2], (f16)v[3]};
            *(f16x4*)(outp + (size_t)pix*CC + oc) = h;
        }
    }
}

// ---------------------------------------------------------------------------
// reduce: aggT[zi][pix][c] bf16 = sum of active job slabs (invrec pre-folded)
// ---------------------------------------------------------------------------
__global__ __launch_bounds__(256)
void reduce_agg_kernel(const f16* __restrict__ Pm, const float* __restrict__ mask,
                       short* __restrict__ aggT, int n_l1)
{
    int zi = blockIdx.y;                 // b*n_l1 + l1
    int b = zi / n_l1, l1 = zi % n_l1;
    if (l1 != 0 && mask[b*LL + l1] == 0.f) return;
    int pix = blockIdx.x*256 + threadIdx.x;
    bool act[4];
    #pragma unroll
    for (int j=0;j<LL;++j) act[j] = (mask[b*LL + j] != 0.f);
    const f16* base = Pm + (size_t)(zi*5)*HW*CC + (size_t)pix*CC;
    short* dst = aggT + (size_t)zi*HW*CC + (size_t)pix*CC;
    for (int cg=0; cg<16; ++cg) {
        float s[8];
        f16x8 e = *(const f16x8*)(base + (size_t)4*HW*CC + cg*8);
        #pragma unroll
        for (int j8=0;j8<8;++j8) s[j8] = (float)e[j8];
        #pragma unroll
        for (int j=0;j<4;++j) {
            if (!act[j]) continue;
            f16x8 p = *(const f16x8*)(base + (size_t)j*HW*CC + cg*8);
            #pragma unroll
            for (int j8=0;j8<8;++j8) s[j8] += (float)p[j8];
        }
        unsigned int pk[4];
        #pragma unroll
        for (int j2=0;j2<4;++j2)
            pk[j2] = f2b(s[2*j2]) | (f2b(s[2*j2+1])<<16);
        u32x4 w = {pk[0],pk[1],pk[2],pk[3]};
        *(u32x4*)(dst + cg*8) = w;
    }
}

// ===========================================================================
// gru conv (round-10 wave structure, both gates in ONE dispatch via
// blockIdx.y): full K=256 per block (stage feat; MFMA; stage agg; MFMA),
// acc[4][4], fragment-order A, 1:4 A-load:MFMA.  Raw conv -> f16 slab
// Pg[gate][z]; activation applied by combine_kernel.
// ===========================================================================
__global__ __launch_bounds__(256,3)
void gru_conv_kernel(const short* __restrict__ featT, const short* __restrict__ aggT,
                     const float* __restrict__ mask,
                     const short* __restrict__ WuF, const short* __restrict__ WcF,
                     f16* __restrict__ Pg, int n_l1)
{
    int z = blockIdx.z;
    int b = z / n_l1, l1 = z % n_l1;
    if (l1 != 0 && mask[b*LL + l1] == 0.f) return;
    int gate = blockIdx.y;               // 0 = U, 1 = C (block-uniform)

    int ty = blockIdx.x / 11, tx = blockIdx.x % 11;
    int y0 = ty*8, x0 = tx*16;
    int tid = threadIdx.x;
    int wid = tid >> 6, lane = tid & 63;
    int wr = wid >> 1, wc = wid & 1;
    int l15 = lane & 15, hi = lane >> 4;

    __shared__ short lt[180*128];  // 45 KB

    f32x4 acc[4][4];
    #pragma unroll
    for (int m=0;m<4;++m)
        #pragma unroll
        for (int n=0;n<4;++n) acc[m][n] = (f32x4){0.f,0.f,0.f,0.f};

    const short* WF = (gate==0) ? WuF : WcF;
    const short* wlane = WF + l15*32 + hi*8;

    for (int s = 0; s < 2; ++s) {
        const short* in = (s==0) ? featT + (size_t)(b*LL + l1)*HW*CC
                                 : aggT  + (size_t)(b*n_l1 + l1)*HW*CC;
        if (s) __syncthreads();           // MFMA readers of stage-0 done
        for (int i = tid; i < 180*16; i += 256) {
            int row = i >> 4, cg = i & 15;
            int yy = row / 18, xx = row - yy*18;
            int gy = y0 - 1 + yy, gx = x0 - 1 + xx;
            u32x4 val = {0,0,0,0};
            if (gy>=0 && gy<HH && gx>=0 && gx<WWID)
                val = *(const u32x4*)(in + (size_t)(gy*WWID+gx)*CC + cg*8);
            int byte = row*256 + ((cg*16) ^ ((row&7)<<4));
            *(u32x4*)((char*)lt + byte) = val;
        }
        __syncthreads();

        int kqbase = s*4;
        __builtin_amdgcn_s_setprio(1);
        for (int tap=0; tap<9; ++tap) {
            int dy = tap/3, dx = tap - dy*3;
            #pragma unroll
            for (int kk=0; kk<4; ++kk) {
                const short* wt = wlane + (size_t)(((tap*8 + kqbase + kk)*8 + wr*4))*512;
                bf16x8 av[4];
                #pragma unroll
                for (int m=0;m<4;++m)
                    av[m] = *(const bf16x8*)(wt + m*512);
                bf16x8 bv[4];
                #pragma unroll
                for (int n=0;n<4;++n) {
                    int pos = (wc*4 + n + dy)*18 + dx + l15;
                    int byte = pos*256 + ((kk*64 + hi*16) ^ ((pos&7)<<4));
                    bv[n] = *(const bf16x8*)((const char*)lt + byte);
                }
                #pragma unroll
                for (int m=0;m<4;++m)
                    #pragma unroll
                    for (int n=0;n<4;++n)
                        acc[m][n] = __builtin_amdgcn_mfma_f32_16x16x32_bf16(
                            av[m], bv[n], acc[m][n], 0, 0, 0);
            }
        }
        __builtin_amdgcn_s_setprio(0);
    }

    f16* outp = Pg + ((size_t)(gate*(BB*LL) + z))*HW*CC;
    #pragma unroll
    for (int m=0;m<4;++m)
        #pragma unroll
        for (int n=0;n<4;++n) {
            int pix = (y0 + wc*4 + n)*WWID + x0 + l15;
            int oc  = wr*64 + m*16 + hi*4;
            f32x4 v = acc[m][n];
            f16x4 h = {(f16)v[0], (f16)v[1], (f16)v[2], (f16)v[3]};
            *(f16x4*)(outp + (size_t)pix*CC + oc) = h;
        }
}

// ---------------------------------------------------------------------------
// combine: h = sigmoid(U+bgU) * tanh(C+bc) -> bf16 [z][pix][ch]
// ---------------------------------------------------------------------------
__global__ __launch_bounds__(256)
void combine_kernel(const f16* __restrict__ Pg, const float* __restrict__ mask,
                    const float* __restrict__ bgU, const float* __restrict__ bc,
                    short* __restrict__ outT, int n_l1)
{
    int z = blockIdx.y;
    int b = z / n_l1, l1 = z % n_l1;
    if (l1 != 0 && mask[b*LL + l1] == 0.f) return;
    int pix = blockIdx.x*256 + threadIdx.x;
    size_t poff = (size_t)pix*CC;
    const f16* U = Pg + ((size_t)(0*(BB*LL) + z))*HW*CC + poff;
    const f16* C = Pg + ((size_t)(1*(BB*LL) + z))*HW*CC + poff;
    short* dst = outT + (size_t)z*HW*CC + poff;
    for (int cg=0; cg<16; ++cg) {
        f16x8 u8 = *(const f16x8*)(U + cg*8);
        f16x8 c8 = *(const f16x8*)(C + cg*8);
        unsigned int pk[4];
        #pragma unroll
        for (int jj=0; jj<4; ++jj) {
            float r[2];
            #pragma unroll
            for (int t=0; t<2; ++t) {
                int j = jj*2 + t;
                float uu = (float)u8[j] + bgU[cg*8 + j];
                float cc = (float)c8[j] + bc[cg*8 + j];
                float sig = 1.f/(1.f + expf(-uu));
                r[t] = sig * tanhf(cc);
            }
            pk[jj] = f2b(r[0]) | (f2b(r[1])<<16);
        }
        u32x4 w = {pk[0],pk[1],pk[2],pk[3]};
        *(u32x4*)(dst + cg*8) = w;
    }
}

// ---------------------------------------------------------------------------
// final 1x1 MLP:  out[b][oc][pix] = sum_c feat2T[b][pix][c]*W[oc][c] + bias
// ---------------------------------------------------------------------------
__global__ __launch_bounds__(256)
void mlp_kernel(const short* __restrict__ feat2T, const float* __restrict__ Wm,
                const float* __restrict__ bmlp, float* __restrict__ out)
{
    int b = blockIdx.z, oc0 = blockIdx.y*32;
    int pix = blockIdx.x*256 + threadIdx.x;
    const short* src = feat2T + (size_t)b*HW*CC + (size_t)pix*CC;
    float acc[32];
    #pragma unroll
    for (int oc=0;oc<32;++oc) acc[oc]=0.f;
    for (int c8 = 0; c8 < 16; ++c8) {
        bf16x8 v = *(const bf16x8*)(src + c8*8);
        float f[8];
        #pragma unroll
        for (int j=0;j<8;++j) f[j] = b2f(v[j]);
        #pragma unroll
        for (int oc=0; oc<32; ++oc) {
            const float* w = Wm + (size_t)(oc0+oc)*CC + c8*8;
            #pragma unroll
            for (int j=0;j<8;++j) acc[oc] = fmaf(f[j], w[j], acc[oc]);
        }
    }
    #pragma unroll
    for (int oc=0;oc<32;++oc)
        out[((size_t)b*CC + oc0+oc)*HW + pix] = acc[oc] + bmlp[oc0+oc];
}

// ---------------------------------------------------------------------------
extern "C" void kernel_launch(void* const* d_in, const int* in_sizes, int n_in,
                              void* d_out, int out_size, void* d_ws, size_t ws_size,
                              hipStream_t stream)
{
    const float* x     = (const float*)d_in[0];
    const float* mask  = (const float*)d_in[1];
    const float* T     = (const float*)d_in[2];
    const int*   recl  = (const int*)  d_in[3];
    const float* Wmsg  = (const float*)d_in[4];
    const float* bmsg  = (const float*)d_in[5];
    const float* Wg    = (const float*)d_in[6];
    const float* bg    = (const float*)d_in[7];
    const float* Wc    = (const float*)d_in[8];
    const float* bc    = (const float*)d_in[9];
    const float* Wmlp  = (const float*)d_in[10];
    const float* bmlp  = (const float*)d_in[11];
    float* out = (float*)d_out;

    char* w = (char*)d_ws;
    short* xT   = (short*)w;          w += (size_t)BB*LL*HW*CC*2;      // 17.3 MB
    float* fac  = (float*)w;          w += (size_t)32*HW*4;            // 1.1 MB
    short* WmF  = (short*)w;          w += (size_t)9*128*256*2;
    short* WuF  = (short*)w;          w += (size_t)9*128*256*2;
    short* WcF  = (short*)w;          w += (size_t)9*128*256*2;
    f16*   Pm   = (f16*)w;            w += (size_t)40*HW*CC*2;         // 86.5 MB
    f16*   Pg   = (f16*)w;            w += (size_t)2*BB*LL*HW*CC*2;    // 34.6 MB
    short* aggT = (short*)w;          w += (size_t)BB*LL*HW*CC*2;      // 17.3 MB
    short* f1T  = (short*)w;          w += (size_t)BB*LL*HW*CC*2;      // 17.3 MB
    short* f2T  = (short*)w;          w += (size_t)BB*HW*CC*2;         // 4.3 MB

    repack3_kernel<<<dim3(1152,3), 256, 0, stream>>>(Wmsg, Wg, Wc, WmF, WuF, WcF);
    to_bf16T_kernel<<<dim3(33, BB*LL), 256, 0, stream>>>(x, xT);
    fac_kernel<<<dim3(33, 32), 256, 0, stream>>>(T, mask, fac);

    // ---- iteration 1 ----
    msg_conv_kernel<<<dim3(66, 1, BB*LL*5), 256, 0, stream>>>(
        xT, T, fac, mask, recl, WmF, bmsg, Pm, LL);
    reduce_agg_kernel<<<dim3(33, BB*LL), 256, 0, stream>>>(Pm, mask, aggT, LL);
    gru_conv_kernel<<<dim3(66, 2, BB*LL), 256, 0, stream>>>(
        xT, aggT, mask, WuF, WcF, Pg, LL);
    combine_kernel<<<dim3(33, BB*LL), 256, 0, stream>>>(
        Pg, mask, bg + CC, bc, f1T, LL);

    // ---- iteration 2 (only l1=0 consumed) ----
    msg_conv_kernel<<<dim3(66, 1, BB*5), 256, 0, stream>>>(
        f1T, T, fac, mask, recl, WmF, bmsg, Pm, 1);
    reduce_agg_kernel<<<dim3(33, BB), 256, 0, stream>>>(Pm, mask, aggT, 1);
    gru_conv_kernel<<<dim3(66, 2, BB), 256, 0, stream>>>(
        f1T, aggT, mask, WuF, WcF, Pg, 1);
    combine_kernel<<<dim3(33, BB), 256, 0, stream>>>(
        Pg, mask, bg + CC, bc, f2T, 1);

    // ---- final MLP ----
    mlp_kernel<<<dim3(33, 4, BB), 256, 0, stream>>>(f2T, Wmlp, bmlp, out);
}

// Round 13
// 530.980 us; speedup vs baseline: 1.0653x; 1.0107x over previous
//
#include <hip/hip_runtime.h>
#include <math.h>

#define BB 2
#define LL 4
#define CC 128
#define HH 48
#define WWID 176
#define HW 8448   // 48*176

typedef _Float16 f16;
typedef __attribute__((ext_vector_type(8))) _Float16 f16x8;
typedef __attribute__((ext_vector_type(4))) _Float16 f16x4;
typedef __attribute__((ext_vector_type(2))) _Float16 f16x2;
typedef __attribute__((ext_vector_type(4))) float f32x4;
typedef __attribute__((ext_vector_type(4))) unsigned int u32x4;
typedef __attribute__((ext_vector_type(2))) unsigned int u32x2;

// inverse affine from a 4x4 pairwise T block
__device__ __forceinline__ void ainv_from(const float* __restrict__ t, float* a)
{
    float R00=t[0], R01=t[1], t0=t[3];
    float R10=t[4], R11=t[5], t1=t[7];
    float tx = t0 * 0.625f;              // / (RATIO*DS) = /1.6
    float ty = t1 * 0.625f;
    const float cx = WWID/2.0f, cy = HH/2.0f;
    float ftx = cx - (R00*cx + R01*cy) + tx;
    float fty = cy - (R10*cx + R11*cy) + ty;
    float det = R00*R11 - R01*R10;
    float inv = 1.0f/det;
    float i00 =  R11*inv, i01 = -R01*inv, i10 = -R10*inv, i11 = R00*inv;
    a[0]=i00; a[1]=i01; a[2]=-(i00*ftx + i01*fty);
    a[3]=i10; a[4]=i11; a[5]=-(i10*ftx + i11*fty);
}

// ---------------------------------------------------------------------------
// Repack conv weights (OIHW fp32) -> MFMA-fragment order, f16:
//   blk = (tap*8 + kq)*8 + ocblk ; within blk: [l15 16][hi 4][j 8]
// ---------------------------------------------------------------------------
__global__ __launch_bounds__(256)
void repack3_kernel(const float* __restrict__ Wm, const float* __restrict__ Wg,
                    const float* __restrict__ Wc,
                    f16* __restrict__ WmF, f16* __restrict__ WuF,
                    f16* __restrict__ WcF)
{
    int which = blockIdx.y;
    const float* src = (which==0) ? Wm : (which==1) ? Wg : Wc;
    f16* dst         = (which==0) ? WmF : (which==1) ? WuF : WcF;
    int oc_off = (which==1) ? 128 : 0;     // u-gate rows live at [C, 2C)
    int stride = (which==0) ? 256 : 384;
    int idx = blockIdx.x*256 + threadIdx.x;
    if (idx >= 9*8*8*512) return;
    int j     = idx & 7;
    int hi    = (idx >> 3) & 3;
    int l15   = (idx >> 5) & 15;
    int ocblk = (idx >> 9) & 7;
    int kq    = (idx >> 12) & 7;
    int tap   = idx >> 15;
    int oc  = ocblk*16 + l15;
    int cin = kq*32 + hi*8 + j;
    dst[idx] = (f16)src[((size_t)(oc_off+oc)*stride + cin)*9 + tap];
}

// ---------------------------------------------------------------------------
// x [bl][c][pix] fp32  ->  xT [bl][pix][c] f16
// ---------------------------------------------------------------------------
__global__ __launch_bounds__(256)
void to_f16T_kernel(const float* __restrict__ x, f16* __restrict__ xT)
{
    int bl = blockIdx.y;
    int pix = blockIdx.x*256 + threadIdx.x;   // grid.x = 33
    const float* src = x + (size_t)bl*CC*HW + pix;
    f16* dst = xT + (size_t)bl*HW*CC + (size_t)pix*CC;
    for (int g = 0; g < 8; ++g) {
        f16x8 v0, v1;
        #pragma unroll
        for (int c2 = 0; c2 < 8; ++c2) {
            v0[c2] = (f16)src[(size_t)(g*16 + c2    )*HW];
            v1[c2] = (f16)src[(size_t)(g*16 + 8 + c2)*HW];
        }
        *(f16x8*)(dst + g*16    ) = v0;
        *(f16x8*)(dst + g*16 + 8) = v1;
    }
}

// ---------------------------------------------------------------------------
// roi factor maps: fac[slot=(b,l2,l1)][pix]  (already * mask[l2])
// ---------------------------------------------------------------------------
__global__ __launch_bounds__(256)
void fac_kernel(const float* __restrict__ T, const float* __restrict__ mask,
                float* __restrict__ fac)
{
    int slot = blockIdx.y;                    // (b<<4)|(l2<<2)|l1
    int pix = blockIdx.x*256 + threadIdx.x;
    int b = slot >> 4, l2 = (slot >> 2) & 3;
    float mk = mask[b*LL + l2];
    float a[6];
    ainv_from(T + slot*16, a);
    float gx = (float)(pix % WWID), gy = (float)(pix / WWID);
    float sx = a[0]*gx + a[1]*gy + a[2];
    float sy = a[3]*gx + a[4]*gy + a[5];
    float x0 = floorf(sx), y0 = floorf(sy);
    float wx = sx-x0, wy = sy-y0;
    int xi=(int)x0, yi=(int)y0;
    bool vx0 = xi>=0 && xi<WWID, vx1 = xi+1>=0 && xi+1<WWID;
    bool vy0 = yi>=0 && yi<HH,   vy1 = yi+1>=0 && yi+1<HH;
    float r = (vx0&&vy0?(1.f-wx)*(1.f-wy):0.f) + (vx1&&vy0?wx*(1.f-wy):0.f)
            + (vx0&&vy1?(1.f-wx)*wy:0.f)       + (vx1&&vy1?wx*wy:0.f);
    fac[(size_t)slot*HW + pix] = r*mk;
}

// ===========================================================================
// msg conv, one JOB per block-z: z = (b, l1, src).  src<4: sender l2=src
// (gather-staged unless l2==l1), weights cin[0:128), scale fac[l2 slot].
// src==4: ego, weights cin[128:256), scale facsum, +bias.
// block = 128 oc x (8y x 16x) px, 4 waves, K=128x9taps, fragment-order A,
// packed-f16 gather blend.  Output fp16 Pm[z][pix][oc] (fac/bias/invrec folded).
// ===========================================================================
__global__ __launch_bounds__(256,3)
void msg_conv_kernel(const f16* __restrict__ featT, const float* __restrict__ T,
                     const float* __restrict__ fac, const float* __restrict__ mask,
                     const int* __restrict__ reclen,
                     const f16* __restrict__ WmF, const float* __restrict__ bm,
                     f16* __restrict__ Pm, int n_l1)
{
    int z = blockIdx.z;
    int b = z / (n_l1*5);
    int rem = z - b*(n_l1*5);
    int l1 = rem / 5, src = rem % 5;
    if (l1 != 0 && mask[b*LL + l1] == 0.f) return;   // output never consumed
    bool ego = (src == 4);
    int l2 = ego ? l1 : src;
    if (!ego && mask[b*LL + l2] == 0.f) return;      // sender inactive
    bool gather = (!ego) && (l2 != l1);

    int ty = blockIdx.x / 11, tx = blockIdx.x % 11;
    int y0 = ty*8, x0 = tx*16;
    int tid = threadIdx.x;
    int wid = tid >> 6, lane = tid & 63;
    int wr = wid >> 1, wc = wid & 1;
    int l15 = lane & 15, hi = lane >> 4;

    __shared__ short lt[180*128];        // 45 KB
    __shared__ float tw[4][192];
    __shared__ int   tof[4][192];

    const f16* in = featT + (size_t)(b*LL + l2)*HW*CC;

    if (gather) {
        // per-row bilinear taps (once), then 4-tap packed-f16 blend staging
        float a6[6];
        ainv_from(T + ((b*LL + l2)*LL + l1)*16, a6);
        float a0=a6[0],a1=a6[1],a2=a6[2],a3=a6[3],a4=a6[4],a5=a6[5];
        for (int r = tid; r < 180; r += 256) {
            int yy = r / 18, xx = r - yy*18;
            int gy = y0 - 1 + yy, gx = x0 - 1 + xx;
            float w00=0.f,w10=0.f,w01=0.f,w11=0.f;
            int o00=0,o10=0,o01=0,o11=0;
            if (gy>=0 && gy<HH && gx>=0 && gx<WWID) {
                float sx = a0*(float)gx + a1*(float)gy + a2;
                float sy = a3*(float)gx + a4*(float)gy + a5;
                float xf = floorf(sx), yf = floorf(sy);
                float wx = sx-xf, wyv = sy-yf;
                int xi=(int)xf, yi=(int)yf;
                bool vx0=xi>=0&&xi<WWID, vx1=xi+1>=0&&xi+1<WWID;
                bool vy0=yi>=0&&yi<HH,   vy1=yi+1>=0&&yi+1<HH;
                int xc0=min(max(xi,0),WWID-1), xc1=min(max(xi+1,0),WWID-1);
                int yc0=min(max(yi,0),HH-1),   yc1=min(max(yi+1,0),HH-1);
                o00=(yc0*WWID+xc0)*CC; o10=(yc0*WWID+xc1)*CC;
                o01=(yc1*WWID+xc0)*CC; o11=(yc1*WWID+xc1)*CC;
                w00=(vx0&&vy0)?(1.f-wx)*(1.f-wyv):0.f;
                w10=(vx1&&vy0)?wx*(1.f-wyv):0.f;
                w01=(vx0&&vy1)?(1.f-wx)*wyv:0.f;
                w11=(vx1&&vy1)?wx*wyv:0.f;
            }
            tw[0][r]=w00; tw[1][r]=w10; tw[2][r]=w01; tw[3][r]=w11;
            tof[0][r]=o00; tof[1][r]=o10; tof[2][r]=o01; tof[3][r]=o11;
        }
        __syncthreads();
        for (int i = tid; i < 180*16; i += 256) {
            int row = i >> 4, cg = i & 15;
            f16 h00=(f16)tw[0][row], h10=(f16)tw[1][row];
            f16 h01=(f16)tw[2][row], h11=(f16)tw[3][row];
            f16x2 W00={h00,h00}, W10={h10,h10}, W01={h01,h01}, W11={h11,h11};
            int o00=tof[0][row], o10=tof[1][row], o01=tof[2][row], o11=tof[3][row];
            f16x8 t00 = *(const f16x8*)(in + o00 + cg*8);
            f16x8 t10 = *(const f16x8*)(in + o10 + cg*8);
            f16x8 t01 = *(const f16x8*)(in + o01 + cg*8);
            f16x8 t11 = *(const f16x8*)(in + o11 + cg*8);
            const f16x2* p00 = (const f16x2*)&t00;
            const f16x2* p10 = (const f16x2*)&t10;
            const f16x2* p01 = (const f16x2*)&t01;
            const f16x2* p11 = (const f16x2*)&t11;
            f16x8 outv;
            f16x2* po = (f16x2*)&outv;
            #pragma unroll
            for (int q=0;q<4;++q)
                po[q] = p00[q]*W00 + p10[q]*W10 + p01[q]*W01 + p11[q]*W11;
            int byte = row*256 + ((cg*16) ^ ((row&7)<<4));
            *(f16x8*)((char*)lt + byte) = outv;
        }
    } else {
        for (int i = tid; i < 180*16; i += 256) {
            int row = i >> 4, cg = i & 15;
            int yy = row / 18, xx = row - yy*18;
            int gy = y0 - 1 + yy, gx = x0 - 1 + xx;
            u32x4 val = {0,0,0,0};
            if (gy>=0 && gy<HH && gx>=0 && gx<WWID)
                val = *(const u32x4*)(in + (size_t)(gy*WWID+gx)*CC + cg*8);
            int byte = row*256 + ((cg*16) ^ ((row&7)<<4));
            *(u32x4*)((char*)lt + byte) = val;
        }
    }
    __syncthreads();

    f32x4 acc[4][4];
    #pragma unroll
    for (int m=0;m<4;++m)
        #pragma unroll
        for (int n=0;n<4;++n) acc[m][n] = (f32x4){0.f,0.f,0.f,0.f};

    const int kqbase = ego ? 4 : 0;
    const f16* wlane = WmF + l15*32 + hi*8;
    __builtin_amdgcn_s_setprio(1);
    for (int tap=0; tap<9; ++tap) {
        int dy = tap/3, dx = tap - dy*3;
        #pragma unroll
        for (int kk=0; kk<4; ++kk) {
            const f16* wt = wlane + (size_t)(((tap*8 + kqbase + kk)*8 + wr*4))*512;
            f16x8 av[4];
            #pragma unroll
            for (int m=0;m<4;++m)
                av[m] = *(const f16x8*)(wt + m*512);
            f16x8 bv[4];
            #pragma unroll
            for (int n=0;n<4;++n) {
                int pos = (wc*4 + n + dy)*18 + dx + l15;
                int byte = pos*256 + ((kk*64 + hi*16) ^ ((pos&7)<<4));
                bv[n] = *(const f16x8*)((const char*)lt + byte);
            }
            #pragma unroll
            for (int m=0;m<4;++m)
                #pragma unroll
                for (int n=0;n<4;++n)
                    acc[m][n] = __builtin_amdgcn_mfma_f32_16x16x32_f16(
                        av[m], bv[n], acc[m][n], 0, 0, 0);
        }
    }
    __builtin_amdgcn_s_setprio(0);

    // per-pixel scale: fac (pair) or facsum (ego), times invrec (precision)
    float invrec = 1.0f / (float)reclen[b];
    float fsc[4];
    if (ego) {
        #pragma unroll
        for (int n=0;n<4;++n) fsc[n] = 0.f;
        for (int j=0;j<LL;++j) {
            if (mask[b*LL + j] == 0.f) continue;
            const float* fp = fac + (size_t)(b*16 + j*4 + l1)*HW;
            #pragma unroll
            for (int n=0;n<4;++n)
                fsc[n] += fp[(y0 + wc*4 + n)*WWID + x0 + l15];
        }
    } else {
        const float* fp = fac + (size_t)(b*16 + l2*4 + l1)*HW;
        #pragma unroll
        for (int n=0;n<4;++n)
            fsc[n] = fp[(y0 + wc*4 + n)*WWID + x0 + l15];
    }
    #pragma unroll
    for (int n=0;n<4;++n) fsc[n] *= invrec;

    f16* outp = Pm + (size_t)z*HW*CC;
    #pragma unroll
    for (int m=0;m<4;++m) {
        f32x4 b4 = {0.f,0.f,0.f,0.f};
        if (ego) b4 = *(const f32x4*)(bm + wr*64 + m*16 + hi*4);
        #pragma unroll
        for (int n=0;n<4;++n) {
            int pix = (y0 + wc*4 + n)*WWID + x0 + l15;
            int oc  = wr*64 + m*16 + hi*4;
            f32x4 v = (acc[m][n] + b4) * fsc[n];
            f16x4 h = {(f16)v[0], (f16)v[1], (f16)v[2], (f16)v[3]};
            *(f16x4*)(outp + (size_t)pix*CC + oc) = h;
        }
    }
}

// ---------------------------------------------------------------------------
// reduce: aggT[zi][pix][c] f16 = sum of active job slabs (invrec pre-folded)
// ---------------------------------------------------------------------------
__global__ __launch_bounds__(256)
void reduce_agg_kernel(const f16* __restrict__ Pm, const float* __restrict__ mask,
                       f16* __restrict__ aggT, int n_l1)
{
    int zi = blockIdx.y;                 // b*n_l1 + l1
    int b = zi / n_l1, l1 = zi % n_l1;
    if (l1 != 0 && mask[b*LL + l1] == 0.f) return;
    int pix = blockIdx.x*256 + threadIdx.x;
    bool act[4];
    #pragma unroll
    for (int j=0;j<LL;++j) act[j] = (mask[b*LL + j] != 0.f);
    const f16* base = Pm + (size_t)(zi*5)*HW*CC + (size_t)pix*CC;
    f16* dst = aggT + (size_t)zi*HW*CC + (size_t)pix*CC;
    for (int cg=0; cg<16; ++cg) {
        float s[8];
        f16x8 e = *(const f16x8*)(base + (size_t)4*HW*CC + cg*8);
        #pragma unroll
        for (int j8=0;j8<8;++j8) s[j8] = (float)e[j8];
        #pragma unroll
        for (int j=0;j<4;++j) {
            if (!act[j]) continue;
            f16x8 p = *(const f16x8*)(base + (size_t)j*HW*CC + cg*8);
            #pragma unroll
            for (int j8=0;j8<8;++j8) s[j8] += (float)p[j8];
        }
        f16x8 o;
        #pragma unroll
        for (int j8=0;j8<8;++j8) o[j8] = (f16)s[j8];
        *(f16x8*)(dst + cg*8) = o;
    }
}

// ===========================================================================
// gru conv (round-10 wave structure, both gates in ONE dispatch via
// blockIdx.y): full K=256 per block (stage feat; MFMA; stage agg; MFMA),
// acc[4][4], fragment-order A, 1:4 A-load:MFMA.  Raw conv -> f16 slab
// Pg[gate][z]; activation applied by combine_kernel.
// ===========================================================================
__global__ __launch_bounds__(256,3)
void gru_conv_kernel(const f16* __restrict__ featT, const f16* __restrict__ aggT,
                     const float* __restrict__ mask,
                     const f16* __restrict__ WuF, const f16* __restrict__ WcF,
                     f16* __restrict__ Pg, int n_l1)
{
    int z = blockIdx.z;
    int b = z / n_l1, l1 = z % n_l1;
    if (l1 != 0 && mask[b*LL + l1] == 0.f) return;
    int gate = blockIdx.y;               // 0 = U, 1 = C (block-uniform)

    int ty = blockIdx.x / 11, tx = blockIdx.x % 11;
    int y0 = ty*8, x0 = tx*16;
    int tid = threadIdx.x;
    int wid = tid >> 6, lane = tid & 63;
    int wr = wid >> 1, wc = wid & 1;
    int l15 = lane & 15, hi = lane >> 4;

    __shared__ short lt[180*128];  // 45 KB

    f32x4 acc[4][4];
    #pragma unroll
    for (int m=0;m<4;++m)
        #pragma unroll
        for (int n=0;n<4;++n) acc[m][n] = (f32x4){0.f,0.f,0.f,0.f};

    const f16* WF = (gate==0) ? WuF : WcF;
    const f16* wlane = WF + l15*32 + hi*8;

    for (int s = 0; s < 2; ++s) {
        const f16* in = (s==0) ? featT + (size_t)(b*LL + l1)*HW*CC
                               : aggT  + (size_t)(b*n_l1 + l1)*HW*CC;
        if (s) __syncthreads();           // MFMA readers of stage-0 done
        for (int i = tid; i < 180*16; i += 256) {
            int row = i >> 4, cg = i & 15;
            int yy = row / 18, xx = row - yy*18;
            int gy = y0 - 1 + yy, gx = x0 - 1 + xx;
            u32x4 val = {0,0,0,0};
            if (gy>=0 && gy<HH && gx>=0 && gx<WWID)
                val = *(const u32x4*)(in + (size_t)(gy*WWID+gx)*CC + cg*8);
            int byte = row*256 + ((cg*16) ^ ((row&7)<<4));
            *(u32x4*)((char*)lt + byte) = val;
        }
        __syncthreads();

        int kqbase = s*4;
        __builtin_amdgcn_s_setprio(1);
        for (int tap=0; tap<9; ++tap) {
            int dy = tap/3, dx = tap - dy*3;
            #pragma unroll
            for (int kk=0; kk<4; ++kk) {
                const f16* wt = wlane + (size_t)(((tap*8 + kqbase + kk)*8 + wr*4))*512;
                f16x8 av[4];
                #pragma unroll
                for (int m=0;m<4;++m)
                    av[m] = *(const f16x8*)(wt + m*512);
                f16x8 bv[4];
                #pragma unroll
                for (int n=0;n<4;++n) {
                    int pos = (wc*4 + n + dy)*18 + dx + l15;
                    int byte = pos*256 + ((kk*64 + hi*16) ^ ((pos&7)<<4));
                    bv[n] = *(const f16x8*)((const char*)lt + byte);
                }
                #pragma unroll
                for (int m=0;m<4;++m)
                    #pragma unroll
                    for (int n=0;n<4;++n)
                        acc[m][n] = __builtin_amdgcn_mfma_f32_16x16x32_f16(
                            av[m], bv[n], acc[m][n], 0, 0, 0);
            }
        }
        __builtin_amdgcn_s_setprio(0);
    }

    f16* outp = Pg + ((size_t)(gate*(BB*LL) + z))*HW*CC;
    #pragma unroll
    for (int m=0;m<4;++m)
        #pragma unroll
        for (int n=0;n<4;++n) {
            int pix = (y0 + wc*4 + n)*WWID + x0 + l15;
            int oc  = wr*64 + m*16 + hi*4;
            f32x4 v = acc[m][n];
            f16x4 h = {(f16)v[0], (f16)v[1], (f16)v[2], (f16)v[3]};
            *(f16x4*)(outp + (size_t)pix*CC + oc) = h;
        }
}

// ---------------------------------------------------------------------------
// combine: h = sigmoid(U+bgU) * tanh(C+bc) -> f16 [z][pix][ch]
// ---------------------------------------------------------------------------
__global__ __launch_bounds__(256)
void combine_kernel(const f16* __restrict__ Pg, const float* __restrict__ mask,
                    const float* __restrict__ bgU, const float* __restrict__ bc,
                    f16* __restrict__ outT, int n_l1)
{
    int z = blockIdx.y;
    int b = z / n_l1, l1 = z % n_l1;
    if (l1 != 0 && mask[b*LL + l1] == 0.f) return;
    int pix = blockIdx.x*256 + threadIdx.x;
    size_t poff = (size_t)pix*CC;
    const f16* U = Pg + ((size_t)(0*(BB*LL) + z))*HW*CC + poff;
    const f16* C = Pg + ((size_t)(1*(BB*LL) + z))*HW*CC + poff;
    f16* dst = outT + (size_t)z*HW*CC + poff;
    for (int cg=0; cg<16; ++cg) {
        f16x8 u8 = *(const f16x8*)(U + cg*8);
        f16x8 c8 = *(const f16x8*)(C + cg*8);
        f16x8 o;
        #pragma unroll
        for (int j=0; j<8; ++j) {
            float uu = (float)u8[j] + bgU[cg*8 + j];
            float cc = (float)c8[j] + bc[cg*8 + j];
            float sig = 1.f/(1.f + expf(-uu));
            o[j] = (f16)(sig * tanhf(cc));
        }
        *(f16x8*)(dst + cg*8) = o;
    }
}

// ---------------------------------------------------------------------------
// final 1x1 MLP:  out[b][oc][pix] = sum_c feat2T[b][pix][c]*W[oc][c] + bias
// ---------------------------------------------------------------------------
__global__ __launch_bounds__(256)
void mlp_kernel(const f16* __restrict__ feat2T, const float* __restrict__ Wm,
                const float* __restrict__ bmlp, float* __restrict__ out)
{
    int b = blockIdx.z, oc0 = blockIdx.y*32;
    int pix = blockIdx.x*256 + threadIdx.x;
    const f16* src = feat2T + (size_t)b*HW*CC + (size_t)pix*CC;
    float acc[32];
    #pragma unroll
    for (int oc=0;oc<32;++oc) acc[oc]=0.f;
    for (int c8 = 0; c8 < 16; ++c8) {
        f16x8 v = *(const f16x8*)(src + c8*8);
        float f[8];
        #pragma unroll
        for (int j=0;j<8;++j) f[j] = (float)v[j];
        #pragma unroll
        for (int oc=0; oc<32; ++oc) {
            const float* w = Wm + (size_t)(oc0+oc)*CC + c8*8;
            #pragma unroll
            for (int j=0;j<8;++j) acc[oc] = fmaf(f[j], w[j], acc[oc]);
        }
    }
    #pragma unroll
    for (int oc=0;oc<32;++oc)
        out[((size_t)b*CC + oc0+oc)*HW + pix] = acc[oc] + bmlp[oc0+oc];
}

// ---------------------------------------------------------------------------
extern "C" void kernel_launch(void* const* d_in, const int* in_sizes, int n_in,
                              void* d_out, int out_size, void* d_ws, size_t ws_size,
                              hipStream_t stream)
{
    const float* x     = (const float*)d_in[0];
    const float* mask  = (const float*)d_in[1];
    const float* T     = (const float*)d_in[2];
    const int*   recl  = (const int*)  d_in[3];
    const float* Wmsg  = (const float*)d_in[4];
    const float* bmsg  = (const float*)d_in[5];
    const float* Wg    = (const float*)d_in[6];
    const float* bg    = (const float*)d_in[7];
    const float* Wc    = (const float*)d_in[8];
    const float* bc    = (const float*)d_in[9];
    const float* Wmlp  = (const float*)d_in[10];
    const float* bmlp  = (const float*)d_in[11];
    float* out = (float*)d_out;

    char* w = (char*)d_ws;
    f16*   xT   = (f16*)w;            w += (size_t)BB*LL*HW*CC*2;      // 17.3 MB
    float* fac  = (float*)w;          w += (size_t)32*HW*4;            // 1.1 MB
    f16*   WmF  = (f16*)w;            w += (size_t)9*128*256*2;
    f16*   WuF  = (f16*)w;            w += (size_t)9*128*256*2;
    f16*   WcF  = (f16*)w;            w += (size_t)9*128*256*2;
    f16*   Pm   = (f16*)w;            w += (size_t)40*HW*CC*2;         // 86.5 MB
    f16*   Pg   = (f16*)w;            w += (size_t)2*BB*LL*HW*CC*2;    // 34.6 MB
    f16*   aggT = (f16*)w;            w += (size_t)BB*LL*HW*CC*2;      // 17.3 MB
    f16*   f1T  = (f16*)w;            w += (size_t)BB*LL*HW*CC*2;      // 17.3 MB
    f16*   f2T  = (f16*)w;            w += (size_t)BB*HW*CC*2;         // 4.3 MB

    repack3_kernel<<<dim3(1152,3), 256, 0, stream>>>(Wmsg, Wg, Wc, WmF, WuF, WcF);
    to_f16T_kernel<<<dim3(33, BB*LL), 256, 0, stream>>>(x, xT);
    fac_kernel<<<dim3(33, 32), 256, 0, stream>>>(T, mask, fac);

    // ---- iteration 1 ----
    msg_conv_kernel<<<dim3(66, 1, BB*LL*5), 256, 0, stream>>>(
        xT, T, fac, mask, recl, WmF, bmsg, Pm, LL);
    reduce_agg_kernel<<<dim3(33, BB*LL), 256, 0, stream>>>(Pm, mask, aggT, LL);
    gru_conv_kernel<<<dim3(66, 2, BB*LL), 256, 0, stream>>>(
        xT, aggT, mask, WuF, WcF, Pg, LL);
    combine_kernel<<<dim3(33, BB*LL), 256, 0, stream>>>(
        Pg, mask, bg + CC, bc, f1T, LL);

    // ---- iteration 2 (only l1=0 consumed) ----
    msg_conv_kernel<<<dim3(66, 1, BB*5), 256, 0, stream>>>(
        f1T, T, fac, mask, recl, WmF, bmsg, Pm, 1);
    reduce_agg_kernel<<<dim3(33, BB), 256, 0, stream>>>(Pm, mask, aggT, 1);
    gru_conv_kernel<<<dim3(66, 2, BB), 256, 0, stream>>>(
        f1T, aggT, mask, WuF, WcF, Pg, 1);
    combine_kernel<<<dim3(33, BB), 256, 0, stream>>>(
        Pg, mask, bg + CC, bc, f2T, 1);

    // ---- final MLP ----
    mlp_kernel<<<dim3(33, 4, BB), 256, 0, stream>>>(f2T, Wmlp, bmlp, out);
}